// Round 5
// baseline (3388.882 us; speedup 1.0000x reference)
//
#include <hip/hip_runtime.h>

// ---------------------------------------------------------------------------
// Stacked BiLSTM autoencoder.  B=512, T=256, F=64, N=128.
//
// v4: MFMA recurrence (bf16 split-precision) + fp32 feed GEMMs.
//  - Recurrence z_t = xz_t + h@U runs on matrix cores: h split hi+lo (exact),
//    U split hi+lo -> 3-term MFMA (~fp32 accuracy). e1 keeps x@W in-kernel
//    (x split hi+lo @ W_hi). Per step: MFMA -> zslab(LDS) -> barrier -> gate
//    (VALU) -> h frags back to LDS -> barrier.  2 barriers/step.
//  - h frags stored in MFMA A-fragment layout [k/8][row][8] with word-XOR
//    swizzle so gate scatter-writes and frag reads are conflict-free.
//  - Feed GEMMs xz = A@W + b (fp32 VALU, proven round-4 kernel) hoisted for
//    e2/d2 (T-chunked, TC from ws_size) and d1 (z@W once, step_stride=0).
//  - Blocks: (B/16, 2 dirs) = 64; latency-bound per step, not throughput.
// ---------------------------------------------------------------------------

#define THREADS 512

using f32x4 = __attribute__((ext_vector_type(4))) float;
using bfrag = __attribute__((ext_vector_type(8))) short;

__device__ __forceinline__ float sigf(float x) { return 1.0f / (1.0f + __expf(-x)); }
__device__ __forceinline__ unsigned short f2bf(float f) {
    unsigned u = __float_as_uint(f);
    u += 0x7FFFu + ((u >> 16) & 1u);
    return (unsigned short)(u >> 16);
}
__device__ __forceinline__ float bf2f(unsigned short h) {
    return __uint_as_float(((unsigned)h) << 16);
}
// ushort offset of the 16B fragment word (kc, row), XOR-swizzled for banks
__device__ __forceinline__ int fragw(int kc, int r) {
    return ((kc * 16 + r) ^ (kc & 7)) * 8;
}

// UH: hidden units; XK: in-kernel x@W depth (e1 only); LASTONLY: emit final h.
template<int UH, int XK, bool LASTONLY>
__global__ __launch_bounds__(THREADS, 2)
void lstm_rec(const float* __restrict__ xz, const size_t xz_ds, const size_t xz_ss,
              const float* __restrict__ xin,
              const float* __restrict__ Uf, const float* __restrict__ Ub,
              const float* __restrict__ Wf, const float* __restrict__ Wb,
              const float* __restrict__ bf, const float* __restrict__ bb,
              float* __restrict__ out,
              float* __restrict__ stc, float* __restrict__ sth,
              const int T, const int t0, const int TCc, const int FIRST, const int LASTC)
{
    constexpr int NCOL = 4 * UH;
    constexpr int NS   = NCOL / 8;           // cols per wave
    constexpr int NT   = NS / 16;            // 16-col MFMA tiles per wave
    constexpr int KT   = UH / 32;            // k-tiles over h
    constexpr int XKT  = XK / 32;            // k-tiles over x
    constexpr int PPT  = 16 * UH / THREADS;  // gate (b,u) pairs per thread
    constexpr int BQS  = THREADS / UH;       // batch stride between pairs
    constexpr int ZP   = NCOL + 4;           // padded zslab row
    static_assert(XK == 0 || XK == 64, "x path");
    static_assert(NT >= 1 && KT >= 1 && PPT >= 1, "shape");

    const int dir = blockIdx.y;
    const bool rev = (dir != 0);
    const float* __restrict__ U  = dir ? Ub : Uf;
    const float* __restrict__ Wm = dir ? Wb : Wf;
    const float* __restrict__ bs = dir ? bb : bf;

    const int b0  = blockIdx.x * 16;
    const int tid = threadIdx.x;
    const int wv  = tid >> 6;
    const int l   = tid & 63;
    const int lr  = l & 15;                  // A row / B col within tile
    const int kg  = l >> 4;                  // k-group (8 elems each)
    const int c0  = wv * NS;

    __shared__ unsigned short hh_hi[UH * 16], hh_lo[UH * 16];
    __shared__ unsigned short xh_hi[XK > 0 ? 2 * XK * 16 : 8];
    __shared__ unsigned short xh_lo[XK > 0 ? 2 * XK * 16 : 8];
    __shared__ float zs[16 * ZP];

    // ---- recurrent weights -> register B-fragments (hi + lo) ----
    bfrag whi[NT][KT], wlo[NT][KT];
    #pragma unroll
    for (int nt = 0; nt < NT; ++nt)
        #pragma unroll
        for (int kt = 0; kt < KT; ++kt) {
            const int col = c0 + nt * 16 + lr;
            #pragma unroll
            for (int i = 0; i < 8; ++i) {
                const int k = kt * 32 + kg * 8 + i;
                const float w = U[(size_t)k * NCOL + col];
                const unsigned short h = f2bf(w);
                whi[nt][kt][i] = (short)h;
                wlo[nt][kt][i] = (short)f2bf(w - bf2f(h));
            }
        }
    bfrag wxhi[NT][XKT > 0 ? XKT : 1];
    float biasr[NT];
    if constexpr (XK > 0) {
        #pragma unroll
        for (int nt = 0; nt < NT; ++nt) {
            const int col = c0 + nt * 16 + lr;
            #pragma unroll
            for (int kt = 0; kt < XKT; ++kt)
                #pragma unroll
                for (int i = 0; i < 8; ++i)
                    wxhi[nt][kt][i] = (short)f2bf(Wm[(size_t)(kt * 32 + kg * 8 + i) * NCOL + col]);
            biasr[nt] = bs[col];
        }
    }

    const int ut = tid % UH;                 // gate unit (constant over pairs)
    float cst[PPT];

    // ---- init / restore state ----
    if (FIRST) {
        for (int i = tid; i < UH * 16; i += THREADS) { hh_hi[i] = 0; hh_lo[i] = 0; }
        #pragma unroll
        for (int q = 0; q < PPT; ++q) cst[q] = 0.0f;
    } else {
        #pragma unroll
        for (int q = 0; q < PPT; ++q) {
            const int b = tid / UH + q * BQS;
            const float hv = sth[((size_t)dir * 512 + b0 + b) * UH + ut];
            const unsigned short hi = f2bf(hv);
            const unsigned short lo = f2bf(hv - bf2f(hi));
            hh_hi[fragw(ut >> 3, b) + (ut & 7)] = hi;
            hh_lo[fragw(ut >> 3, b) + (ut & 7)] = lo;
            cst[q] = stc[((size_t)dir * 512 + b0 + b) * UH + ut];
        }
    }
    if constexpr (XK > 0) {                  // stage x for p=0 into buf 0
        const int gt0 = rev ? (T - 1 - t0) : t0;
        const int bb = tid >> 5, f = (tid & 31) * 2;
        const float2 xv = *(const float2*)&xin[((size_t)(b0 + bb) * T + gt0) * XK + f];
        const unsigned short h0 = f2bf(xv.x), h1 = f2bf(xv.y);
        const unsigned short l0 = f2bf(xv.x - bf2f(h0)), l1 = f2bf(xv.y - bf2f(h1));
        const int off = fragw(f >> 3, bb) + (f & 7);
        *(unsigned*)&xh_hi[off] = (unsigned)h0 | ((unsigned)h1 << 16);
        *(unsigned*)&xh_lo[off] = (unsigned)l0 | ((unsigned)l1 << 16);
    }
    __syncthreads();

    for (int p = 0; p < TCc; ++p) {
        const int gt = rev ? (T - 1 - (t0 + p)) : (t0 + p);

        // ---- issue next-step x loads / this-step xz loads (hide latency) ----
        float2 xnext;
        const bool havex = (XK > 0) && (p + 1 < TCc);
        if (havex) {
            const int gtn = rev ? (T - 1 - (t0 + p + 1)) : (t0 + p + 1);
            const int bb = tid >> 5, f = (tid & 31) * 2;
            xnext = *(const float2*)&xin[((size_t)(b0 + bb) * T + gtn) * XK + f];
        }
        float xzr[PPT][4];
        if constexpr (XK == 0) {
            const float* xrow = xz + (size_t)dir * xz_ds + (size_t)p * xz_ss;
            #pragma unroll
            for (int q = 0; q < PPT; ++q) {
                const int b = tid / UH + q * BQS;
                const float* r = xrow + (size_t)(b0 + b) * NCOL + ut;
                #pragma unroll
                for (int g = 0; g < 4; ++g) xzr[q][g] = r[g * UH];
            }
        }

        // ---- MFMA phase ----
        f32x4 acc[NT];
        #pragma unroll
        for (int nt = 0; nt < NT; ++nt) {
            if constexpr (XK > 0) acc[nt] = f32x4{biasr[nt], biasr[nt], biasr[nt], biasr[nt]};
            else                  acc[nt] = f32x4{0.f, 0.f, 0.f, 0.f};
        }
        #pragma unroll
        for (int kt = 0; kt < KT; ++kt) {
            const bfrag ahi = *(const bfrag*)&hh_hi[fragw(kt * 4 + kg, lr)];
            const bfrag alo = *(const bfrag*)&hh_lo[fragw(kt * 4 + kg, lr)];
            #pragma unroll
            for (int nt = 0; nt < NT; ++nt) {
                acc[nt] = __builtin_amdgcn_mfma_f32_16x16x32_bf16(ahi, whi[nt][kt], acc[nt], 0, 0, 0);
                acc[nt] = __builtin_amdgcn_mfma_f32_16x16x32_bf16(alo, whi[nt][kt], acc[nt], 0, 0, 0);
                acc[nt] = __builtin_amdgcn_mfma_f32_16x16x32_bf16(ahi, wlo[nt][kt], acc[nt], 0, 0, 0);
            }
        }
        if constexpr (XK > 0) {
            const int xb = (p & 1) * XK * 16;
            #pragma unroll
            for (int kt = 0; kt < XKT; ++kt) {
                const bfrag xhi = *(const bfrag*)&xh_hi[xb + fragw(kt * 4 + kg, lr)];
                const bfrag xlo = *(const bfrag*)&xh_lo[xb + fragw(kt * 4 + kg, lr)];
                #pragma unroll
                for (int nt = 0; nt < NT; ++nt) {
                    acc[nt] = __builtin_amdgcn_mfma_f32_16x16x32_bf16(xhi, wxhi[nt][kt], acc[nt], 0, 0, 0);
                    acc[nt] = __builtin_amdgcn_mfma_f32_16x16x32_bf16(xlo, wxhi[nt][kt], acc[nt], 0, 0, 0);
                }
            }
        }
        // C/D layout (verified): col = l&15, row = (l>>4)*4 + q
        #pragma unroll
        for (int nt = 0; nt < NT; ++nt)
            #pragma unroll
            for (int qq = 0; qq < 4; ++qq)
                zs[(kg * 4 + qq) * ZP + c0 + nt * 16 + lr] = acc[nt][qq];

        __syncthreads();   // zslab complete; all frag reads of this step done

        if (havex) {       // convert + write x_{p+1} into the other buffer
            const int bb = tid >> 5, f = (tid & 31) * 2;
            const unsigned short h0 = f2bf(xnext.x), h1 = f2bf(xnext.y);
            const unsigned short l0 = f2bf(xnext.x - bf2f(h0)), l1 = f2bf(xnext.y - bf2f(h1));
            const int off = ((p + 1) & 1) * XK * 16 + fragw(f >> 3, bb) + (f & 7);
            *(unsigned*)&xh_hi[off] = (unsigned)h0 | ((unsigned)h1 << 16);
            *(unsigned*)&xh_lo[off] = (unsigned)l0 | ((unsigned)l1 << 16);
        }

        // ---- gate phase ----
        #pragma unroll
        for (int q = 0; q < PPT; ++q) {
            const int b = tid / UH + q * BQS;
            float z0 = zs[b * ZP + 0 * UH + ut];
            float z1 = zs[b * ZP + 1 * UH + ut];
            float z2 = zs[b * ZP + 2 * UH + ut];
            float z3 = zs[b * ZP + 3 * UH + ut];
            if constexpr (XK == 0) { z0 += xzr[q][0]; z1 += xzr[q][1]; z2 += xzr[q][2]; z3 += xzr[q][3]; }
            const float iv = sigf(z0);
            const float fv = sigf(z1);
            const float gv = fmaxf(z2, 0.0f);
            const float ov = sigf(z3);
            const float c  = fv * cst[q] + iv * gv;
            cst[q] = c;
            const float h = ov * fmaxf(c, 0.0f);
            if (!LASTONLY) {
                out[((size_t)(b0 + b) * T + gt) * (2 * UH) + (size_t)dir * UH + ut] = h;
            } else if (LASTC && p == TCc - 1) {
                out[(size_t)(b0 + b) * (2 * UH) + (size_t)dir * UH + ut] = h;
            }
            const unsigned short hi = f2bf(h);
            const unsigned short lo = f2bf(h - bf2f(hi));
            hh_hi[fragw(ut >> 3, b) + (ut & 7)] = hi;
            hh_lo[fragw(ut >> 3, b) + (ut & 7)] = lo;
        }
        __syncthreads();   // h frags ready for next step; zslab free
    }

    // ---- carry state across chunks ----
    #pragma unroll
    for (int q = 0; q < PPT; ++q) {
        const int b = tid / UH + q * BQS;
        const float hv = bf2f(hh_hi[fragw(ut >> 3, b) + (ut & 7)])
                       + bf2f(hh_lo[fragw(ut >> 3, b) + (ut & 7)]);
        sth[((size_t)dir * 512 + b0 + b) * UH + ut] = hv;
        stc[((size_t)dir * 512 + b0 + b) * UH + ut] = cst[q];
    }
}

// xz = A @ W_dir + b_dir  (fp32, 64x64 tile, 4x4 micro). TMAP: rows are
// (lt,b) with per-dir time reversal; else rows are plain batch (d1's z@W).
template<int K, int NC, bool TMAP>
__global__ __launch_bounds__(256, 2)
void xz_gemm(const float* __restrict__ A,
             const float* __restrict__ Wf, const float* __restrict__ Wb,
             const float* __restrict__ bf, const float* __restrict__ bb,
             float* __restrict__ xz, const int T, const int t0, const int TC)
{
    const int dir = blockIdx.z;
    const float* __restrict__ W = dir ? Wb : Wf;
    const float* __restrict__ bs = dir ? bb : bf;
    const int row0 = blockIdx.x * 64;
    const int col0 = blockIdx.y * 64;
    const int tid = threadIdx.x;
    const int tx = tid & 15, ty = tid >> 4;

    __shared__ float As[64][17];
    __shared__ float Bs[16][64];

    float acc[4][4];
    #pragma unroll
    for (int i = 0; i < 4; ++i)
        #pragma unroll
        for (int j = 0; j < 4; ++j) acc[i][j] = 0.0f;

    const int r_st = tid >> 2;
    const int kq   = (tid & 3) * 4;
    const int rowA = row0 + r_st;
    const float* Arow;
    if (TMAP) {
        const int ltA = rowA >> 9, bA = rowA & 511;
        const int gtA = dir ? (T - 1 - (t0 + ltA)) : (t0 + ltA);
        Arow = A + ((size_t)bA * T + gtA) * K;
    } else {
        Arow = A + (size_t)rowA * K;
    }
    const int kr = tid >> 4, c4 = (tid & 15) * 4;

    for (int kc = 0; kc < K; kc += 16) {
        *(float4*)&As[r_st][kq] = *(const float4*)&Arow[kc + kq];
        *(float4*)&Bs[kr][c4]   = *(const float4*)&W[(size_t)(kc + kr) * NC + col0 + c4];
        __syncthreads();
        #pragma unroll
        for (int kk = 0; kk < 16; ++kk) {
            float a[4];
            #pragma unroll
            for (int i = 0; i < 4; ++i) a[i] = As[ty * 4 + i][kk];
            const float4 bv = *(const float4*)&Bs[kk][tx * 4];
            #pragma unroll
            for (int i = 0; i < 4; ++i) {
                acc[i][0] = fmaf(a[i], bv.x, acc[i][0]);
                acc[i][1] = fmaf(a[i], bv.y, acc[i][1]);
                acc[i][2] = fmaf(a[i], bv.z, acc[i][2]);
                acc[i][3] = fmaf(a[i], bv.w, acc[i][3]);
            }
        }
        __syncthreads();
    }
    const float4 bv = *(const float4*)&bs[col0 + tx * 4];
    #pragma unroll
    for (int i = 0; i < 4; ++i) {
        const int row = row0 + ty * 4 + i;
        float4 o;
        o.x = acc[i][0] + bv.x; o.y = acc[i][1] + bv.y;
        o.z = acc[i][2] + bv.z; o.w = acc[i][3] + bv.w;
        if (TMAP) {
            const int lt = row >> 9, b = row & 511;
            *(float4*)&xz[(((size_t)dir * TC + lt) * 512 + b) * NC + col0 + tx * 4] = o;
        } else {
            *(float4*)&xz[((size_t)dir * 512 + row) * NC + col0 + tx * 4] = o;
        }
    }
}

// out(rows,64) = h(rows,256) @ Wd(256,64) + bd
__global__ __launch_bounds__(256, 1)
void dense_out(const float* __restrict__ h, const float* __restrict__ Wd,
               const float* __restrict__ bd, float* __restrict__ out, const int rows)
{
    const int tid = threadIdx.x;
    const int lc  = (tid & 15) * 4;
    const size_t row = (size_t)blockIdx.x * 16 + (tid >> 4);
    if (row >= (size_t)rows) return;
    const float* hr = h + row * 256;
    float4 a;
    a.x = bd[lc]; a.y = bd[lc + 1]; a.z = bd[lc + 2]; a.w = bd[lc + 3];
    #pragma unroll 4
    for (int k = 0; k < 256; k += 4) {
        const float4 hv = *reinterpret_cast<const float4*>(&hr[k]);
        const float4 w0 = *reinterpret_cast<const float4*>(&Wd[(size_t)(k + 0) * 64 + lc]);
        const float4 w1 = *reinterpret_cast<const float4*>(&Wd[(size_t)(k + 1) * 64 + lc]);
        const float4 w2 = *reinterpret_cast<const float4*>(&Wd[(size_t)(k + 2) * 64 + lc]);
        const float4 w3 = *reinterpret_cast<const float4*>(&Wd[(size_t)(k + 3) * 64 + lc]);
        a.x = fmaf(hv.x, w0.x, a.x); a.y = fmaf(hv.x, w0.y, a.y); a.z = fmaf(hv.x, w0.z, a.z); a.w = fmaf(hv.x, w0.w, a.w);
        a.x = fmaf(hv.y, w1.x, a.x); a.y = fmaf(hv.y, w1.y, a.y); a.z = fmaf(hv.y, w1.z, a.z); a.w = fmaf(hv.y, w1.w, a.w);
        a.x = fmaf(hv.z, w2.x, a.x); a.y = fmaf(hv.z, w2.y, a.y); a.z = fmaf(hv.z, w2.z, a.z); a.w = fmaf(hv.z, w2.w, a.w);
        a.x = fmaf(hv.w, w3.x, a.x); a.y = fmaf(hv.w, w3.y, a.y); a.z = fmaf(hv.w, w3.z, a.z); a.w = fmaf(hv.w, w3.w, a.w);
    }
    *reinterpret_cast<float4*>(&out[row * 64 + lc]) = a;
}

extern "C" void kernel_launch(void* const* d_in, const int* in_sizes, int n_in,
                              void* d_out, int out_size, void* d_ws, size_t ws_size,
                              hipStream_t stream)
{
    (void)in_sizes; (void)n_in; (void)out_size;
    constexpr int B = 512, T = 256;

    const size_t n_h1 = (size_t)B * T * 256;
    const size_t n_h2 = (size_t)B * T * 128;
    const size_t n_z  = (size_t)B * 128;
    const size_t n_st = 2 * ((size_t)2 * B * 64) + 2 * ((size_t)2 * B * 128);
    const size_t base = n_h1 + n_h2 + n_z + n_st;
    int TC = 0;
    for (int tc : {64, 32, 16}) {
        if ((base + (size_t)tc * 2 * B * 512) * sizeof(float) <= ws_size) { TC = tc; break; }
    }
    if (!TC) return;                               // clean fail, no OOB
    const int NCH = T / TC;

    const float* x    = (const float*)d_in[0];
    const float* e1fW = (const float*)d_in[1];
    const float* e1fU = (const float*)d_in[2];
    const float* e1fb = (const float*)d_in[3];
    const float* e1bW = (const float*)d_in[4];
    const float* e1bU = (const float*)d_in[5];
    const float* e1bb = (const float*)d_in[6];
    const float* e2fW = (const float*)d_in[7];
    const float* e2fU = (const float*)d_in[8];
    const float* e2fb = (const float*)d_in[9];
    const float* e2bW = (const float*)d_in[10];
    const float* e2bU = (const float*)d_in[11];
    const float* e2bb = (const float*)d_in[12];
    const float* d1fW = (const float*)d_in[13];
    const float* d1fU = (const float*)d_in[14];
    const float* d1fb = (const float*)d_in[15];
    const float* d1bW = (const float*)d_in[16];
    const float* d1bU = (const float*)d_in[17];
    const float* d1bb = (const float*)d_in[18];
    const float* d2fW = (const float*)d_in[19];
    const float* d2fU = (const float*)d_in[20];
    const float* d2fb = (const float*)d_in[21];
    const float* d2bW = (const float*)d_in[22];
    const float* d2bU = (const float*)d_in[23];
    const float* d2bb = (const float*)d_in[24];
    const float* Wd   = (const float*)d_in[25];
    const float* bd   = (const float*)d_in[26];
    float* out = (float*)d_out;

    float* ws   = (float*)d_ws;
    float* h1   = ws;                               // also h3
    float* h2   = h1 + n_h1;
    float* zv   = h2 + n_h2;
    float* st   = zv + n_z;
    float* stcE = st;
    float* sthE = stcE + (size_t)2 * B * 64;
    float* stcD = sthE + (size_t)2 * B * 64;
    float* sthD = stcD + (size_t)2 * B * 128;
    float* xzb  = st + n_st;                        // xz chunks; d1 feed aliases
    float* xzd1 = xzb;
    float* h3   = h1;

    const dim3 rgrid(B / 16, 2), rblk(THREADS);

    // e1: in-kernel x@W (XK=64) + h@U, full T -> h1
    lstm_rec<128, 64, false><<<rgrid, rblk, 0, stream>>>(
        nullptr, 0, 0, x, e1fU, e1bU, e1fW, e1bW, e1fb, e1bb,
        h1, stcD, sthD, T, 0, T, 1, 1);

    // e2: chunked fp32 feed GEMM + MFMA recurrence (final h only -> zv)
    for (int c = 0; c < NCH; ++c) {
        xz_gemm<256, 256, true><<<dim3(TC * B / 64, 256 / 64, 2), 256, 0, stream>>>(
            h1, e2fW, e2bW, e2fb, e2bb, xzb, T, c * TC, TC);
        lstm_rec<64, 0, true><<<rgrid, rblk, 0, stream>>>(
            xzb, (size_t)TC * 512 * 256, (size_t)512 * 256, nullptr,
            e2fU, e2bU, nullptr, nullptr, nullptr, nullptr,
            zv, stcE, sthE, T, c * TC, TC, c == 0, c == NCH - 1);
    }

    // d1: z@W once (step_stride = 0), then full-T recurrence -> h2
    xz_gemm<128, 256, false><<<dim3(B / 64, 256 / 64, 2), 256, 0, stream>>>(
        zv, d1fW, d1bW, d1fb, d1bb, xzd1, T, 0, 1);
    lstm_rec<64, 0, false><<<rgrid, rblk, 0, stream>>>(
        xzd1, (size_t)512 * 256, 0, nullptr,
        d1fU, d1bU, nullptr, nullptr, nullptr, nullptr,
        h2, stcE, sthE, T, 0, T, 1, 1);

    // d2: chunked feed GEMM + MFMA recurrence -> h3
    for (int c = 0; c < NCH; ++c) {
        xz_gemm<128, 512, true><<<dim3(TC * B / 64, 512 / 64, 2), 256, 0, stream>>>(
            h2, d2fW, d2bW, d2fb, d2bb, xzb, T, c * TC, TC);
        lstm_rec<128, 0, false><<<rgrid, rblk, 0, stream>>>(
            xzb, (size_t)TC * 512 * 512, (size_t)512 * 512, nullptr,
            d2fU, d2bU, nullptr, nullptr, nullptr, nullptr,
            h3, stcD, sthD, T, c * TC, TC, c == 0, c == NCH - 1);
    }

    dense_out<<<(B * T + 15) / 16, 256, 0, stream>>>(h3, Wd, bd, out, B * T);
}